// Round 1
// baseline (3289.378 us; speedup 1.0000x reference)
//
#include <hip/hip_runtime.h>
#include <hip/hip_bf16.h>
#include <cstdint>

typedef __hip_bfloat16 bf16;
typedef __attribute__((ext_vector_type(8))) short bfrag;   // 8 bf16 = 4 VGPRs
typedef __attribute__((ext_vector_type(4))) float f32x4;

#define NB 65536   // batch rows

// ---------------------------------------------------------------- helpers
__device__ __forceinline__ void gload16(const void* g, void* l) {
    __builtin_amdgcn_global_load_lds((const __attribute__((address_space(1))) void*)g,
                                     (__attribute__((address_space(3))) void*)l, 16, 0, 0);
}
__device__ __forceinline__ f32x4 mfma16(bfrag a, bfrag b, f32x4 c) {
    return __builtin_amdgcn_mfma_f32_16x16x32_bf16(a, b, c, 0, 0, 0);
}

// ---------------------------------------------------------------- prep kernels
__global__ void cast_slice(const float* __restrict__ src, bf16* __restrict__ dst,
                           int rows, int src_cols, int col0, int ncols)
{
    long n = (long)rows * ncols;
    for (long i = blockIdx.x * 256L + threadIdx.x; i < n; i += (long)gridDim.x * 256L) {
        long r = i / ncols; int c = (int)(i - r * ncols);
        dst[i] = __float2bfloat16(src[r * src_cols + col0 + c]);
    }
}

// dst [4 groups][6 pieces][64][256]; pieces 0..2 from ih (cols col0:col0+256), 3..5 from hh
__global__ void perm6(const float* __restrict__ ih, int ih_cols, int col0,
                      const float* __restrict__ hh, bf16* __restrict__ dst)
{
    const long n = 1536L * 256;
    for (long i = blockIdx.x * 256L + threadIdx.x; i < n; i += (long)gridDim.x * 256L) {
        int d = (int)(i >> 8); int c = (int)(i & 255);
        int g = d / 384; int rem = d - g * 384; int p = rem / 64; int r = rem & 63;
        int srow = (p % 3) * 256 + g * 64 + r;
        float v = (p < 3) ? ih[(long)srow * ih_cols + col0 + c]
                          : hh[(long)srow * 256 + c];
        dst[i] = __float2bfloat16(v);
    }
}

// ---------------------------------------------------------------- generic GEMM
// Cout[M,N](bf16) = act( A[M,K](bf16) @ W[N,K](bf16).T + bias + Cadd )
__global__ __launch_bounds__(256, 2)
void gemm_kernel(const bf16* __restrict__ A, int K,
                 const bf16* __restrict__ W, const float* __restrict__ bias,
                 const bf16* __restrict__ Cadd, bf16* __restrict__ Cout,
                 int N, int act)
{
    __shared__ bf16 lA[128 * 32];
    __shared__ bf16 lB[128 * 32];
    const int t = threadIdx.x;
    const int l = t & 63;
    const int w = t >> 6;
    const int wr = w >> 1, wc = w & 1;
    const long m0 = (long)blockIdx.y * 128;
    const int n0 = blockIdx.x * 128;
    const int srow = t >> 2;
    const int scol = (t & 3) * 8;

    f32x4 acc[4][4] = {};
    const int nsteps = K >> 5;
    for (int s = 0; s < nsteps; ++s) {
        const int k0 = s * 32;
        gload16(A + (m0 + srow) * K + k0 + scol,        (char*)lA + t * 16);
        gload16(A + (m0 + 64 + srow) * K + k0 + scol,   (char*)lA + 4096 + t * 16);
        gload16(W + (long)(n0 + srow) * K + k0 + scol,      (char*)lB + t * 16);
        gload16(W + (long)(n0 + 64 + srow) * K + k0 + scol, (char*)lB + 4096 + t * 16);
        __syncthreads();
        bfrag af[4], bfr[4];
        #pragma unroll
        for (int m = 0; m < 4; ++m)
            af[m] = *(const bfrag*)(lA + (wr * 64 + m * 16 + (l & 15)) * 32 + 8 * (l >> 4));
        #pragma unroll
        for (int n = 0; n < 4; ++n)
            bfr[n] = *(const bfrag*)(lB + (wc * 64 + n * 16 + (l & 15)) * 32 + 8 * (l >> 4));
        #pragma unroll
        for (int m = 0; m < 4; ++m)
            #pragma unroll
            for (int n = 0; n < 4; ++n)
                acc[m][n] = mfma16(af[m], bfr[n], acc[m][n]);
        __syncthreads();
    }

    const int colb = n0 + wc * 64 + (l & 15);
    const int rloc = wr * 64 + 4 * (l >> 4);
    #pragma unroll
    for (int m = 0; m < 4; ++m) {
        #pragma unroll
        for (int n = 0; n < 4; ++n) {
            const int c = colb + n * 16;
            const float bb = bias ? bias[c] : 0.0f;
            #pragma unroll
            for (int q = 0; q < 4; ++q) {
                const long r = m0 + rloc + m * 16 + q;
                float v = acc[m][n][q] + bb;
                if (Cadd) v += __bfloat162float(Cadd[r * N + c]);
                if (act == 1) v = 0.5f * v * (1.0f + erff(v * 0.70710678f));
                Cout[r * N + c] = __float2bfloat16(v);
            }
        }
    }
}

// ---------------------------------------------------------------- fused GRU step
// Hout = GRU(Hin) where gi = Gpre + Hin@Wp[g][0..2].T, gh = Hin@Wp[g][3..5].T + bhh
__global__ __launch_bounds__(256, 2)
void gru_fused(const bf16* __restrict__ Hin, const bf16* __restrict__ Gpre,
               const bf16* __restrict__ Wp, const float* __restrict__ bhh,
               bf16* __restrict__ Hout, float* __restrict__ Fout)
{
    __shared__ bf16 lA[64 * 32];
    __shared__ bf16 lW[6 * 64 * 32];
    const int t = threadIdx.x;
    const int l = t & 63;
    const int w = t >> 6;
    const int g = blockIdx.x;
    const long m0 = (long)blockIdx.y * 64;
    const int srow = t >> 2;
    const int scol = (t & 3) * 8;
    const bf16* Wg = Wp + (long)g * 6 * 64 * 256;

    f32x4 acc[6][4] = {};
    for (int s = 0; s < 8; ++s) {
        const int k0 = s * 32;
        gload16(Hin + (m0 + srow) * 256 + k0 + scol, (char*)lA + t * 16);
        #pragma unroll
        for (int p = 0; p < 6; ++p)
            gload16(Wg + (long)(p * 64 + srow) * 256 + k0 + scol,
                    (char*)lW + p * 4096 + t * 16);
        __syncthreads();
        bfrag af[4];
        #pragma unroll
        for (int m = 0; m < 4; ++m)
            af[m] = *(const bfrag*)(lA + (m * 16 + (l & 15)) * 32 + 8 * (l >> 4));
        #pragma unroll
        for (int p = 0; p < 6; ++p) {
            bfrag bw = *(const bfrag*)(lW + p * 2048 + (w * 16 + (l & 15)) * 32 + 8 * (l >> 4));
            #pragma unroll
            for (int m = 0; m < 4; ++m)
                acc[p][m] = mfma16(af[m], bw, acc[p][m]);
        }
        __syncthreads();
    }

    const int u = g * 64 + w * 16 + (l & 15);   // hidden unit 0..255
    const float br = bhh[u], bz = bhh[256 + u], bn = bhh[512 + u];
    #pragma unroll
    for (int m = 0; m < 4; ++m) {
        #pragma unroll
        for (int q = 0; q < 4; ++q) {
            const long r = m0 + m * 16 + 4 * (l >> 4) + q;
            const float gr = __bfloat162float(Gpre[r * 768 + u])       + acc[0][m][q] + acc[3][m][q] + br;
            const float gz = __bfloat162float(Gpre[r * 768 + 256 + u]) + acc[1][m][q] + acc[4][m][q] + bz;
            const float gn = __bfloat162float(Gpre[r * 768 + 512 + u]) + acc[2][m][q];
            const float hn = acc[5][m][q] + bn;
            const float rr = 1.0f / (1.0f + __expf(-gr));
            const float zz = 1.0f / (1.0f + __expf(-gz));
            const float nn = tanhf(gn + rr * hn);
            const float h  = __bfloat162float(Hin[r * 256 + u]);
            const float ho = (1.0f - zz) * nn + zz * h;
            Hout[r * 256 + u] = __float2bfloat16(ho);
            if (Fout) Fout[r * 256 + u] = ho;
        }
    }
}

// ---------------------------------------------------------------- output head
__global__ __launch_bounds__(256)
void head_kernel(const float* __restrict__ zh, const float* __restrict__ g,
                 const float* __restrict__ b, const float* __restrict__ ow,
                 const float* __restrict__ ob, float* __restrict__ out)
{
    const int t = threadIdx.x, l = t & 63, sub = t >> 6;
    const long row = blockIdx.x * 4L + sub;
    const float* zr = zh + row * 256;
    const float4 v = *(const float4*)(zr + l * 4);
    float s  = v.x + v.y + v.z + v.w;
    float sq = v.x * v.x + v.y * v.y + v.z * v.z + v.w * v.w;
    #pragma unroll
    for (int o = 32; o >= 1; o >>= 1) { s += __shfl_xor(s, o, 64); sq += __shfl_xor(sq, o, 64); }
    const float mu = s * (1.0f / 256.0f);
    const float var = sq * (1.0f / 256.0f) - mu * mu;
    const float rs = rsqrtf(var + 1e-5f);
    const float4 gg = *(const float4*)(g + l * 4);
    const float4 bb = *(const float4*)(b + l * 4);
    const float n0 = (v.x - mu) * rs * gg.x + bb.x;
    const float n1 = (v.y - mu) * rs * gg.y + bb.y;
    const float n2 = (v.z - mu) * rs * gg.z + bb.z;
    const float n3 = (v.w - mu) * rs * gg.w + bb.w;
    const float4 w0 = *(const float4*)(ow + l * 4);
    const float4 w1 = *(const float4*)(ow + 256 + l * 4);
    float p0 = n0 * w0.x + n1 * w0.y + n2 * w0.z + n3 * w0.w;
    float p1 = n0 * w1.x + n1 * w1.y + n2 * w1.z + n3 * w1.w;
    #pragma unroll
    for (int o = 32; o >= 1; o >>= 1) { p0 += __shfl_xor(p0, o, 64); p1 += __shfl_xor(p1, o, 64); }
    if (l == 0) { out[row * 2] = p0 + ob[0]; out[row * 2 + 1] = p1 + ob[1]; }
}

// ---------------------------------------------------------------- launch
extern "C" void kernel_launch(void* const* d_in, const int* in_sizes, int n_in,
                              void* d_out, int out_size, void* d_ws, size_t ws_size,
                              hipStream_t stream)
{
    (void)in_sizes; (void)n_in; (void)out_size; (void)ws_size;
    const float* x         = (const float*)d_in[0];
    const float* proj_w    = (const float*)d_in[1];
    const float* proj_b    = (const float*)d_in[2];
    const float* low_w_ih  = (const float*)d_in[3];
    const float* low_w_hh  = (const float*)d_in[4];
    const float* low_b_ih  = (const float*)d_in[5];
    const float* low_b_hh  = (const float*)d_in[6];
    const float* high_w_ih = (const float*)d_in[7];
    const float* high_w_hh = (const float*)d_in[8];
    const float* high_b_ih = (const float*)d_in[9];
    const float* high_b_hh = (const float*)d_in[10];
    const float* ln_g      = (const float*)d_in[11];
    const float* ln_b      = (const float*)d_in[12];
    const float* out_w     = (const float*)d_in[13];
    const float* out_b     = (const float*)d_in[14];

    char* ws = (char*)d_ws;
    size_t off = 0;
    auto alloc = [&](size_t bytes) -> void* {
        void* p = ws + off; off += (bytes + 255) & ~(size_t)255; return p;
    };
    bf16* Wlow  = (bf16*)alloc(1536 * 256 * 2);
    bf16* Whigh = (bf16*)alloc(1536 * 256 * 2);
    bf16* Wx    = (bf16*)alloc(768 * 256 * 2);
    bf16* Wh    = (bf16*)alloc(768 * 256 * 2);
    bf16* Vl    = (bf16*)alloc(768 * 256 * 2);
    bf16* Pw    = (bf16*)alloc(256 * 512 * 2);
    bf16* R1    = (bf16*)alloc((size_t)NB * 768 * 2);   // x_bf16, then Gx
    bf16* Gbuf  = (bf16*)alloc((size_t)NB * 768 * 2);
    bf16* Xemb  = (bf16*)alloc((size_t)NB * 256 * 2);
    bf16* Za    = (bf16*)alloc((size_t)NB * 256 * 2);
    bf16* Zb    = (bf16*)alloc((size_t)NB * 256 * 2);
    bf16* Ha    = (bf16*)alloc((size_t)NB * 256 * 2);
    bf16* Hb    = (bf16*)alloc((size_t)NB * 256 * 2);
    bf16* xbf = R1;
    bf16* Gx  = R1;

    float* out_zh = (float*)d_out;
    float* out_zl = out_zh + (size_t)NB * 256;
    float* out_lg = out_zl + (size_t)NB * 256;

    // weight prep + x cast
    cast_slice<<<256, 256, 0, stream>>>(proj_w, Pw, 256, 512, 0, 512);
    cast_slice<<<256, 256, 0, stream>>>(low_w_ih, Wx, 768, 768, 0, 256);
    cast_slice<<<256, 256, 0, stream>>>(low_w_ih, Wh, 768, 768, 256, 256);
    cast_slice<<<256, 256, 0, stream>>>(high_w_ih, Vl, 768, 512, 0, 256);
    perm6<<<256, 256, 0, stream>>>(low_w_ih, 768, 512, low_w_hh, Wlow);
    perm6<<<256, 256, 0, stream>>>(high_w_ih, 512, 256, high_w_hh, Whigh);
    cast_slice<<<2048, 256, 0, stream>>>(x, xbf, NB, 512, 0, 512);

    // x_embed = gelu(x @ proj_w.T + proj_b)
    gemm_kernel<<<dim3(2, NB / 128), 256, 0, stream>>>(xbf, 512, Pw, proj_b, nullptr, Xemb, 256, 1);
    // Gx = x_embed @ Wx.T + low_b_ih   (overwrites xbf region; xbf is dead)
    gemm_kernel<<<dim3(6, NB / 128), 256, 0, stream>>>(Xemb, 256, Wx, low_b_ih, nullptr, Gx, 768, 0);

    hipMemsetAsync(Za, 0, (size_t)NB * 256 * 2, stream);
    hipMemsetAsync(Ha, 0, (size_t)NB * 256 * 2, stream);

    bf16 *zl = Za, *zl_n = Zb, *zh = Ha, *zh_n = Hb;
    const bf16* Gcur = Gx;
    int step = 0;
    for (int cyc = 0; cyc < 3; ++cyc) {
        for (int tstep = 0; tstep < 4; ++tstep) {
            ++step;
            float* fo = (step == 12) ? out_zl : nullptr;
            gru_fused<<<dim3(4, NB / 64), 256, 0, stream>>>(zl, Gcur, Wlow, low_b_hh, zl_n, fo);
            bf16* tmp = zl; zl = zl_n; zl_n = tmp;
        }
        // Gpre_high = z_l @ Vl.T + high_b_ih
        gemm_kernel<<<dim3(6, NB / 128), 256, 0, stream>>>(zl, 256, Vl, high_b_ih, nullptr, Gbuf, 768, 0);
        float* fo = (cyc == 2) ? out_zh : nullptr;
        gru_fused<<<dim3(4, NB / 64), 256, 0, stream>>>(zh, Gbuf, Whigh, high_b_hh, zh_n, fo);
        bf16* tmp = zh; zh = zh_n; zh_n = tmp;
        if (cyc < 2) {
            // Gxh = Gx + z_h @ Wh.T  (for next cycle's low steps)
            gemm_kernel<<<dim3(6, NB / 128), 256, 0, stream>>>(zh, 256, Wh, nullptr, Gx, Gbuf, 768, 0);
            Gcur = Gbuf;
        }
    }
    head_kernel<<<NB / 4, 256, 0, stream>>>(out_zh, ln_g, ln_b, out_w, out_b, out_lg);
}